// Round 4
// baseline (170.269 us; speedup 1.0000x reference)
//
#include <hip/hip_runtime.h>

#define B_   8
#define C_   256
#define W_   8192
#define F_   256
#define KK   3
#define KC   768            // KK * C_
#define WP   (W_ + 2)       // padded rows in featT (zero row at w=-1 and w=W)
#define COEF 0.03608439182435161f   // 1/sqrt(3*256)

// conv_mod geometry: BM=256 (all of F), BN=256 (w), BK=64, dbuf LDS, 8 waves
#define BN_   256
#define BKc   64
#define NT    12            // 768 / 64 K-tiles
#define ABASE 0
#define BBASE 16384         // ushort offset of B region (A = 256 rows x 64 = 16384)
#define BUFU  32768         // ushorts per buffer (64 KiB); x2 = 128 KiB

using f32x16 = __attribute__((ext_vector_type(16))) float;
using bf16x8 = __attribute__((ext_vector_type(8))) __bf16;

#define AS1(p) ((const __attribute__((address_space(1))) void*)(p))
#define AS3(p) ((__attribute__((address_space(3))) void*)(p))

__device__ __forceinline__ unsigned short f2bf(float x) {
    union { float f; unsigned int u; } v; v.f = x;
    unsigned int u = v.u;
    u += 0x7FFFu + ((u >> 16) & 1u);   // RNE
    return (unsigned short)(u >> 16);
}

// Merged prep: blocks 0..7 compute denom (long pole, dispatched first);
// blocks 8..775 transpose kernel -> kT and zero featT's pad rows.
__global__ __launch_bounds__(256) void prep_w(const float* __restrict__ kern,
                                              const float* __restrict__ style,
                                              unsigned short* __restrict__ kT,
                                              float* __restrict__ denom,
                                              unsigned short* __restrict__ featT) {
    __shared__ float sst[C_];
    if (blockIdx.x < B_) {
        const int b = blockIdx.x, f = threadIdx.x;
        sst[f] = (style[b * C_ + f] + 1.0f) * COEF;
        __syncthreads();
        float sum = 0.f;
#pragma unroll 16
        for (int kc = 0; kc < KC; ++kc) {
            float w = kern[(size_t)kc * F_ + f] * sst[kc & 255];
            sum += w * w;
        }
        denom[b * F_ + f] = rsqrtf(sum);
    } else {
        const int idx = (blockIdx.x - B_) * 256 + threadIdx.x;   // ((k*256)+c)*256 + f
        const int f = idx & 255, kc = idx >> 8;
        kT[(size_t)f * KC + kc] = f2bf(kern[idx] * COEF);
        if (idx < 4096) {       // 8 b * 2 pad rows * 256 c
            const int b = idx >> 9, r = (idx >> 8) & 1, c = idx & 255;
            const size_t row = r ? (size_t)(WP - 1) : 0;
            featT[((size_t)b * WP + row) * C_ + c] = 0;
        }
    }
}

// featT[b][w+1][c] = bf16( feat[b][c][w] * (style[b][c]+1) )
__global__ __launch_bounds__(256) void prep_featT(const float* __restrict__ feat,
                                                  const float* __restrict__ style,
                                                  unsigned short* __restrict__ featT) {
    __shared__ float tile[64][65];   // [w][c], 65 pad -> conflict-free both phases
    const int tid = threadIdx.x;
    const int b = blockIdx.z, c0 = blockIdx.y * 64, w0 = blockIdx.x * 64;

    const int x4 = tid & 15, cl4 = tid >> 4;
#pragma unroll
    for (int p = 0; p < 4; ++p) {
        const int cl = cl4 + p * 16;
        const float s = style[b * C_ + c0 + cl] + 1.0f;
        float4 v = *(const float4*)(feat + ((size_t)b * C_ + c0 + cl) * W_ + w0 + x4 * 4);
        tile[x4 * 4 + 0][cl] = v.x * s;
        tile[x4 * 4 + 1][cl] = v.y * s;
        tile[x4 * 4 + 2][cl] = v.z * s;
        tile[x4 * 4 + 3][cl] = v.w * s;
    }
    __syncthreads();

    const int ch = tid & 7, wr = tid >> 3;   // ch: 8-c chunk, wr: 0..31
#pragma unroll
    for (int p = 0; p < 2; ++p) {
        const int w = wr + p * 32;
        unsigned int pk[4];
#pragma unroll
        for (int j = 0; j < 4; ++j) {
            float v0 = tile[w][ch * 8 + 2 * j];
            float v1 = tile[w][ch * 8 + 2 * j + 1];
            pk[j] = (unsigned int)f2bf(v0) | ((unsigned int)f2bf(v1) << 16);
        }
        uint4 u; u.x = pk[0]; u.y = pk[1]; u.z = pk[2]; u.w = pk[3];
        *(uint4*)(featT + ((size_t)b * WP + (w0 + w + 1)) * C_ + c0 + ch * 8) = u;
    }
}

// Main GEMM-conv, 4-phase counted-vmcnt template: 256(f) x 256(w) block tile,
// 512 threads = 8 waves (2M x 4N), per-wave 128x64 via 4(mi) x 2(ni) of
// 32x32x16 MFMA. BK=64 (rows = 128 B), dbuf LDS 64+64 KiB.
// Phase = (mi-half, kh-half): p0=(mi01,kh01) p1=(mi01,kh23) p2=(mi23,kh01)
// p3=(mi23,kh23) -> uniform 8 ds_read_b128 + 8 MFMA per phase. A groups 1,3
// (rows 64-127 per wave-half) are first needed at p2.
// Staging tile t+1 during iter t: p0 issues A0,A2,B0,B1; p1 issues B2,B3,A1,A3.
// Waits are ALWAYS immediately before a barrier (cross-wave visibility rule —
// a per-wave vmcnt only guarantees anything to OTHER waves after a barrier
// that all waves reached post-wait; round-3's wait-after-barrier raced):
//   p1-end: vmcnt(8)  -> tile t's A1,A3 retired for all waves (needed at p2)
//   p3-end: vmcnt(2)  -> tile t+1's first-6 {A0,A2,B0..B3} retired (needed p0)
// Loads in flight never drain to 0; >=2-phase slack per load.
// Bank swizzle: rows are 128 B -> phys chunk = logical chunk ^ (row&7), applied
// on the global SOURCE for staging (LDS dest linear, rule #21) and on the
// read-side chunk index. Frag reads then hit every bank exactly 8x = the
// structural minimum for a 1024 B wave access (zero excess conflict).
__global__ __launch_bounds__(512, 2) void conv_mod(
        const unsigned short* __restrict__ featT,
        const unsigned short* __restrict__ kT,
        const float* __restrict__ denom,
        float* __restrict__ out) {
    __shared__ __align__(16) unsigned short ring[2 * BUFU];   // 128 KiB

    const int tid  = threadIdx.x;
    const int b    = blockIdx.y;
    const int w0   = blockIdx.x * BN_;
    const int lane = tid & 63, wave = tid >> 6;
    const int wm   = (wave >> 2) * 128;   // wave f-offset (2 M-waves)
    const int wn   = (wave & 3) * 64;     // wave w-offset (4 N-waves)
    const int la   = lane & 31, kq = lane >> 5;

    // ---- staging: block-wide instr g covers rows g*64..g*64+63 (8 KiB).
    //      thread tid -> row g*64+(tid>>3); source supplies logical chunk
    //      (tid&7)^(row&7). LDS dest passed WAVE-UNIFORM (wave*1024 B); HW
    //      writes base + lane*16 -> phys chunk tid&7 at row g*64+(tid>>3). ----
    const int srow = tid >> 3;
    const int sswz = ((tid & 7) ^ (srow & 7)) * 8;
    const unsigned short* aS0 = kT + (size_t)srow * KC + sswz;
    const unsigned short* bS0 = featT + ((size_t)b * WP + w0 + srow) * C_ + sswz;
    const int wdst = wave << 9;          // wave-uniform ushort offset: wave*512

    // ---- frag read offsets: row*64 + ((kh*2+kq)^(row&7))*8, row&7 == la&7 ----
    int ck[4];
#pragma unroll
    for (int kh = 0; kh < 4; ++kh) ck[kh] = ((kh * 2 + kq) ^ (la & 7)) * 8;
    const int ra = (wm + la) * BKc;            // + mi*2048 + ck[kh]
    const int rb = BBASE + (wn + la) * BKc;    // + ni*2048 + ck[kh]

    f32x16 acc[4][2] = {};

#define GLDS_A(g, kc, nb) __builtin_amdgcn_global_load_lds( \
        AS1(aS0 + (size_t)(g) * 64 * KC + (kc)), \
        AS3((nb) + ABASE + (g) * 4096 + wdst), 16, 0, 0)
#define GLDS_B(g, kc, nb) __builtin_amdgcn_global_load_lds( \
        AS1(bS0 + (size_t)(g) * 64 * C_ + (kc)), \
        AS3((nb) + BBASE + (g) * 4096 + wdst), 16, 0, 0)
#define PH_BAR() do { __builtin_amdgcn_s_barrier(); \
                      asm volatile("" ::: "memory"); } while (0)
#define VMW(n) do { __builtin_amdgcn_sched_barrier(0); \
                    asm volatile("s_waitcnt vmcnt(" #n ")" ::: "memory"); } while (0)

    // PHASE(MH, KH2): mi in {MH*2, MH*2+1}, kh in {KH2*2, KH2*2+1}.
#define PHASE(MH, KH2) do { \
        bf16x8 av[2][2], bv[2][2]; \
        _Pragma("unroll") \
        for (int i = 0; i < 2; ++i) { \
            _Pragma("unroll") \
            for (int j = 0; j < 2; ++j) { \
                av[i][j] = *(const bf16x8*)&bf[ra + ((MH) * 2 + i) * 2048 + ck[(KH2) * 2 + j]]; \
                bv[i][j] = *(const bf16x8*)&bf[rb + i * 2048 + ck[(KH2) * 2 + j]]; \
            } \
        } \
        __builtin_amdgcn_s_setprio(1); \
        _Pragma("unroll") \
        for (int j = 0; j < 2; ++j) { \
            _Pragma("unroll") \
            for (int i = 0; i < 2; ++i) { \
                acc[(MH) * 2 + i][0] = __builtin_amdgcn_mfma_f32_32x32x16_bf16(av[i][j], bv[0][j], acc[(MH) * 2 + i][0], 0, 0, 0); \
                acc[(MH) * 2 + i][1] = __builtin_amdgcn_mfma_f32_32x32x16_bf16(av[i][j], bv[1][j], acc[(MH) * 2 + i][1], 0, 0, 0); \
            } \
        } \
        __builtin_amdgcn_s_setprio(0); \
    } while (0)

    // ---- prologue: stage tile 0 in prefix order A0,A2,B0,B1,B2,B3,A1,A3;
    //      vmcnt(2)+barrier -> first-6 visible to all waves, A1,A3 in flight ----
    {
        unsigned short* nb = ring;
        GLDS_A(0, 0, nb); GLDS_A(2, 0, nb);
        GLDS_B(0, 0, nb); GLDS_B(1, 0, nb);
        GLDS_B(2, 0, nb); GLDS_B(3, 0, nb);
        GLDS_A(1, 0, nb); GLDS_A(3, 0, nb);
    }
    VMW(2);
    PH_BAR();

#pragma unroll 1
    for (int t = 0; t < NT; ++t) {
        const unsigned short* bf = ring + (t & 1) * BUFU;
        unsigned short* nb = ring + ((t + 1) & 1) * BUFU;
        // last tile re-stages itself into the dead buffer: keeps per-wave
        // vmcnt counts uniform (no divergent tail), loads are L2-hot.
        const int kn = (t < NT - 1 ? t + 1 : NT - 1) * BKc;

        // ---- p0 (mi01 x kh01): stage A0,A2,B0,B1 of t+1 ----
        GLDS_A(0, kn, nb); GLDS_A(2, kn, nb);
        GLDS_B(0, kn, nb); GLDS_B(1, kn, nb);
        PHASE(0, 0);
        PH_BAR();

        // ---- p1 (mi01 x kh23): stage B2,B3,A1,A3 of t+1; then ensure tile
        //      t's A1,A3 retired (outstanding = t's{A1,A3} + t+1's 8 = 10) ----
        GLDS_B(2, kn, nb); GLDS_B(3, kn, nb);
        GLDS_A(1, kn, nb); GLDS_A(3, kn, nb);
        PHASE(0, 1);
        VMW(8);
        PH_BAR();

        // ---- p2 (mi23 x kh01): reads A groups 1,3 -- guaranteed by p1-end ----
        PHASE(1, 0);
        PH_BAR();

        // ---- p3 (mi23 x kh23): ensure t+1's first-6 retired for next p0
        //      (outstanding = t+1's 8 -> vmcnt(2)) ----
        PHASE(1, 1);
        VMW(2);
        PH_BAR();
    }
    // drain the dummy re-stage before LDS is deallocated at wave end
    asm volatile("s_waitcnt vmcnt(0)" ::: "memory");

    // ---- epilogue: C/D layout for 32x32: col=lane&31,
    //      row=(reg&3)+8*(reg>>2)+4*(lane>>5) [measured m74/m101] ----
    const int bofs = b * F_;
    float* obase = out + (size_t)bofs * W_ + w0;
#pragma unroll
    for (int mi = 0; mi < 4; ++mi) {
#pragma unroll
        for (int r = 0; r < 16; ++r) {
            const int frow = (r & 3) + 8 * (r >> 2) + 4 * kq;
            const int f = wm + mi * 32 + frow;
            const float d = denom[bofs + f];
            float* orow = obase + (size_t)f * W_ + wn + la;
            orow[0]  = acc[mi][0][r] * d;
            orow[32] = acc[mi][1][r] * d;
        }
    }
#undef GLDS_A
#undef GLDS_B
#undef PH_BAR
#undef VMW
#undef PHASE
}

extern "C" void kernel_launch(void* const* d_in, const int* in_sizes, int n_in,
                              void* d_out, int out_size, void* d_ws, size_t ws_size,
                              hipStream_t stream) {
    const float* feature = (const float*)d_in[0];   // [8,256,8192]
    const float* style   = (const float*)d_in[1];   // [8,256]
    const float* kern    = (const float*)d_in[2];   // [3,256,256]
    float* out = (float*)d_out;                     // [8,256,8192]

    // ws layout: kT (384 KiB) | denom (8 KiB) | featT (8*8194*256 bf16 = 32.0 MiB)
    unsigned short* kT    = (unsigned short*)d_ws;
    float*          denom = (float*)((char*)d_ws + (size_t)F_ * KC * 2);
    unsigned short* featT = (unsigned short*)((char*)d_ws + (size_t)F_ * KC * 2 + 8192);

    hipLaunchKernelGGL(prep_w,     dim3(KC + B_), dim3(256), 0, stream,
                       kern, style, kT, denom, featT);
    hipLaunchKernelGGL(prep_featT, dim3(W_ / 64, C_ / 64, B_), dim3(256), 0, stream,
                       feature, style, featT);
    hipLaunchKernelGGL(conv_mod,   dim3(W_ / BN_, B_), dim3(512), 0, stream,
                       featT, kT, denom, out);
}

// Round 5
// 170.087 us; speedup vs baseline: 1.0011x; 1.0011x over previous
//
#include <hip/hip_runtime.h>

#define B_   8
#define C_   256
#define W_   8192
#define F_   256
#define KK   3
#define KC   768            // KK * C_
#define WP   (W_ + 2)       // padded rows in featT (zero row at w=-1 and w=W)
#define COEF 0.03608439182435161f   // 1/sqrt(3*256)

// conv_mod geometry: BM=256 (all of F), BN=256 (w), BK=32, ring-4 LDS, 8 waves
#define BN_    256
#define BKc    32
#define NT     24           // 768 / 32 K-tiles
#define SLOTU  16384        // ushorts per ring slot (32 KiB): A 16 KiB + B 16 KiB
#define BBASEU 8192         // ushort offset of B region within a slot

using f32x16 = __attribute__((ext_vector_type(16))) float;
using bf16x8 = __attribute__((ext_vector_type(8))) __bf16;

#define AS1(p) ((const __attribute__((address_space(1))) void*)(p))
#define AS3(p) ((__attribute__((address_space(3))) void*)(p))

__device__ __forceinline__ unsigned short f2bf(float x) {
    union { float f; unsigned int u; } v; v.f = x;
    unsigned int u = v.u;
    u += 0x7FFFu + ((u >> 16) & 1u);   // RNE
    return (unsigned short)(u >> 16);
}

// Merged prep: blocks 0..7 compute denom (long pole, dispatched first);
// blocks 8..775 transpose kernel -> kT and zero featT's pad rows.
__global__ __launch_bounds__(256) void prep_w(const float* __restrict__ kern,
                                              const float* __restrict__ style,
                                              unsigned short* __restrict__ kT,
                                              float* __restrict__ denom,
                                              unsigned short* __restrict__ featT) {
    __shared__ float sst[C_];
    if (blockIdx.x < B_) {
        const int b = blockIdx.x, f = threadIdx.x;
        sst[f] = (style[b * C_ + f] + 1.0f) * COEF;
        __syncthreads();
        float sum = 0.f;
#pragma unroll 16
        for (int kc = 0; kc < KC; ++kc) {
            float w = kern[(size_t)kc * F_ + f] * sst[kc & 255];
            sum += w * w;
        }
        denom[b * F_ + f] = rsqrtf(sum);
    } else {
        const int idx = (blockIdx.x - B_) * 256 + threadIdx.x;   // ((k*256)+c)*256 + f
        const int f = idx & 255, kc = idx >> 8;
        kT[(size_t)f * KC + kc] = f2bf(kern[idx] * COEF);
        if (idx < 4096) {       // 8 b * 2 pad rows * 256 c
            const int b = idx >> 9, r = (idx >> 8) & 1, c = idx & 255;
            const size_t row = r ? (size_t)(WP - 1) : 0;
            featT[((size_t)b * WP + row) * C_ + c] = 0;
        }
    }
}

// featT[b][w+1][c] = bf16( feat[b][c][w] * (style[b][c]+1) )
__global__ __launch_bounds__(256) void prep_featT(const float* __restrict__ feat,
                                                  const float* __restrict__ style,
                                                  unsigned short* __restrict__ featT) {
    __shared__ float tile[64][65];   // [w][c], 65 pad -> conflict-free both phases
    const int tid = threadIdx.x;
    const int b = blockIdx.z, c0 = blockIdx.y * 64, w0 = blockIdx.x * 64;

    const int x4 = tid & 15, cl4 = tid >> 4;
#pragma unroll
    for (int p = 0; p < 4; ++p) {
        const int cl = cl4 + p * 16;
        const float s = style[b * C_ + c0 + cl] + 1.0f;
        float4 v = *(const float4*)(feat + ((size_t)b * C_ + c0 + cl) * W_ + w0 + x4 * 4);
        tile[x4 * 4 + 0][cl] = v.x * s;
        tile[x4 * 4 + 1][cl] = v.y * s;
        tile[x4 * 4 + 2][cl] = v.z * s;
        tile[x4 * 4 + 3][cl] = v.w * s;
    }
    __syncthreads();

    const int ch = tid & 7, wr = tid >> 3;   // ch: 8-c chunk, wr: 0..31
#pragma unroll
    for (int p = 0; p < 2; ++p) {
        const int w = wr + p * 32;
        unsigned int pk[4];
#pragma unroll
        for (int j = 0; j < 4; ++j) {
            float v0 = tile[w][ch * 8 + 2 * j];
            float v1 = tile[w][ch * 8 + 2 * j + 1];
            pk[j] = (unsigned int)f2bf(v0) | ((unsigned int)f2bf(v1) << 16);
        }
        uint4 u; u.x = pk[0]; u.y = pk[1]; u.z = pk[2]; u.w = pk[3];
        *(uint4*)(featT + ((size_t)b * WP + (w0 + w + 1)) * C_ + c0 + ch * 8) = u;
    }
}

// Main GEMM-conv: 256(f) x 256(w) block tile, 8 waves (2M x 4N), per-wave
// 128x64 via 4(mi) x 2(ni) of 32x32x16 MFMA. BK=32, ring-4 LDS (4 x 32 KiB).
// ONE region per K-tile: {stage tile t+3 (4 global_load_lds) | 12 ds_read_b128
// (8 A + 4 B frags, B read once and reused across all 4 mi -> 0.75 reads/MFMA)
// | setprio(1) 16 MFMA setprio(0) | sched_barrier; vmcnt(8); s_barrier}.
// vmcnt(8): outstanding = t+1(4)+t+2(4)+t+3(4)=12, retire t+1's 4 -> tile t+1
// visible to all waves after the barrier; 8 loads stay in flight (never 0);
// each load has ~3 tile-phases (>3000 cyc) to land (HBM ~900 cyc).
// Ring slot x%4 holds tile x; slot (t+3)&3 was freed at end of t-1. Tail tiles
// re-stage tile 23 into dead slots to keep vmcnt counts uniform.
// Bank swizzle (64 B rows = 16 banks; row parity selects the half): phys chunk
// p at row r holds logical p ^ ((r>>1)&3); applied on the global SOURCE for
// staging (LDS dest linear, rule #21) and on the read-side chunk index. Each
// frag read spreads 64 lanes 8-per-4-bank-window (floor).
__global__ __launch_bounds__(512, 2) void conv_mod(
        const unsigned short* __restrict__ featT,
        const unsigned short* __restrict__ kT,
        const float* __restrict__ denom,
        float* __restrict__ out) {
    __shared__ __align__(16) unsigned short ring[4 * SLOTU];   // 128 KiB

    const int tid  = threadIdx.x;
    const int b    = blockIdx.y;
    const int w0   = blockIdx.x * BN_;
    const int lane = tid & 63, wave = tid >> 6;
    const int wm   = (wave >> 2) * 128;   // wave f-offset (2 M-waves)
    const int wn   = (wave & 3) * 64;     // wave w-offset (4 N-waves)
    const int la   = lane & 31, kq = lane >> 5;

    // ---- staging: call g covers rows g*128..g*128+127 (8 KiB; 4 threads/row).
    //      thread tid -> row g*128+(tid>>2), phys chunk tid&3; source supplies
    //      logical chunk (tid&3)^((row>>1)&3) = (tid&3)^((tid>>3)&3).
    //      LDS dest wave-uniform (wave*1024 B); HW adds lane*16. ----
    const int srow = tid >> 2;
    const int sswz = ((tid & 3) ^ ((tid >> 3) & 3)) * 8;
    const unsigned short* aS0 = kT + (size_t)srow * KC + sswz;
    const unsigned short* bS0 = featT + ((size_t)b * WP + w0 + srow) * C_ + sswz;
    const int wdst = wave << 9;          // wave-uniform ushort offset: wave*512

    // ---- frag read offsets (ushort units, slot-relative): row*32 + chunk*8,
    //      chunk = (j*2+kq) ^ ((row>>1)&3); (row>>1)&3 == (la>>1)&3 since
    //      wm/wn/mi*32/ni*32 are multiples of 32 ----
    int ck2[2];
#pragma unroll
    for (int j = 0; j < 2; ++j) ck2[j] = ((j * 2 + kq) ^ ((la >> 1) & 3)) * 8;
    const int ra0 = (wm + la) * BKc;             // + mi*1024 + ck2[j]
    const int rb0 = BBASEU + (wn + la) * BKc;    // + ni*1024 + ck2[j]

    f32x16 acc[4][2] = {};

#define GLDS_A(g, kc, nb) __builtin_amdgcn_global_load_lds( \
        AS1(aS0 + (size_t)(g) * 128 * KC + (kc)), \
        AS3((nb) + (g) * 4096 + wdst), 16, 0, 0)
#define GLDS_B(g, kc, nb) __builtin_amdgcn_global_load_lds( \
        AS1(bS0 + (size_t)(g) * 128 * C_ + (kc)), \
        AS3((nb) + BBASEU + (g) * 4096 + wdst), 16, 0, 0)
#define STAGE(kc, nb) do { \
        GLDS_A(0, kc, nb); GLDS_A(1, kc, nb); \
        GLDS_B(0, kc, nb); GLDS_B(1, kc, nb); \
    } while (0)

    // ---- prologue: stage tiles 0,1,2 into slots 0,1,2 (12 loads);
    //      vmcnt(8) retires tile 0; barrier publishes it ----
    STAGE(0 * BKc, ring);
    STAGE(1 * BKc, ring + SLOTU);
    STAGE(2 * BKc, ring + 2 * SLOTU);
    __builtin_amdgcn_sched_barrier(0);
    asm volatile("s_waitcnt vmcnt(8)" ::: "memory");
    __builtin_amdgcn_s_barrier();
    asm volatile("" ::: "memory");

#pragma unroll 1
    for (int t = 0; t < NT; ++t) {
        const unsigned short* bf = ring + (t & 3) * SLOTU;
        unsigned short* nb = ring + ((t + 3) & 3) * SLOTU;
        const int tn = (t + 3 < NT) ? t + 3 : NT - 1;   // tail: dummy re-stage

        STAGE(tn * BKc, nb);

        bf16x8 av[4][2], bv[2][2];
#pragma unroll
        for (int j = 0; j < 2; ++j) {
#pragma unroll
            for (int ni = 0; ni < 2; ++ni)
                bv[ni][j] = *(const bf16x8*)&bf[rb0 + ni * 1024 + ck2[j]];
#pragma unroll
            for (int mi = 0; mi < 4; ++mi)
                av[mi][j] = *(const bf16x8*)&bf[ra0 + mi * 1024 + ck2[j]];
        }
        __builtin_amdgcn_s_setprio(1);
#pragma unroll
        for (int j = 0; j < 2; ++j) {
#pragma unroll
            for (int mi = 0; mi < 4; ++mi) {
                acc[mi][0] = __builtin_amdgcn_mfma_f32_32x32x16_bf16(av[mi][j], bv[0][j], acc[mi][0], 0, 0, 0);
                acc[mi][1] = __builtin_amdgcn_mfma_f32_32x32x16_bf16(av[mi][j], bv[1][j], acc[mi][1], 0, 0, 0);
            }
        }
        __builtin_amdgcn_s_setprio(0);

        // wait ALWAYS immediately before the barrier (cross-wave visibility):
        // retire tile t+1's 4 loads for all waves; keep 8 in flight.
        __builtin_amdgcn_sched_barrier(0);
        asm volatile("s_waitcnt vmcnt(8)" ::: "memory");
        __builtin_amdgcn_s_barrier();
        asm volatile("" ::: "memory");
    }
    // drain the dummy re-stages before LDS is deallocated at wave end
    asm volatile("s_waitcnt vmcnt(0)" ::: "memory");

    // ---- epilogue: C/D layout for 32x32: col=lane&31,
    //      row=(reg&3)+8*(reg>>2)+4*(lane>>5) [measured m74/m101] ----
    const int bofs = b * F_;
    float* obase = out + (size_t)bofs * W_ + w0;
#pragma unroll
    for (int mi = 0; mi < 4; ++mi) {
#pragma unroll
        for (int r = 0; r < 16; ++r) {
            const int frow = (r & 3) + 8 * (r >> 2) + 4 * kq;
            const int f = wm + mi * 32 + frow;
            const float d = denom[bofs + f];
            float* orow = obase + (size_t)f * W_ + wn + la;
            orow[0]  = acc[mi][0][r] * d;
            orow[32] = acc[mi][1][r] * d;
        }
    }
#undef GLDS_A
#undef GLDS_B
#undef STAGE
}

extern "C" void kernel_launch(void* const* d_in, const int* in_sizes, int n_in,
                              void* d_out, int out_size, void* d_ws, size_t ws_size,
                              hipStream_t stream) {
    const float* feature = (const float*)d_in[0];   // [8,256,8192]
    const float* style   = (const float*)d_in[1];   // [8,256]
    const float* kern    = (const float*)d_in[2];   // [3,256,256]
    float* out = (float*)d_out;                     // [8,256,8192]

    // ws layout: kT (384 KiB) | denom (8 KiB) | featT (8*8194*256 bf16 = 32.0 MiB)
    unsigned short* kT    = (unsigned short*)d_ws;
    float*          denom = (float*)((char*)d_ws + (size_t)F_ * KC * 2);
    unsigned short* featT = (unsigned short*)((char*)d_ws + (size_t)F_ * KC * 2 + 8192);

    hipLaunchKernelGGL(prep_w,     dim3(KC + B_), dim3(256), 0, stream,
                       kern, style, kT, denom, featT);
    hipLaunchKernelGGL(prep_featT, dim3(W_ / 64, C_ / 64, B_), dim3(256), 0, stream,
                       feature, style, featT);
    hipLaunchKernelGGL(conv_mod,   dim3(W_ / BN_, B_), dim3(512), 0, stream,
                       featT, kT, denom, out);
}